// Round 1
// 89.288 us; speedup vs baseline: 1.0015x; 1.0015x over previous
//
#include <hip/hip_runtime.h>

// SE_loss: BCE(se_pred[64,6], class-presence(target[64,512,512] int32)) -> scalar.
//
// Structure: two-phase presence detection.
//  Phase 1: probe the first 16 KB chunk (4096 labels) per batch. For any
//    remotely uniform label distribution this contains all 6 classes
//    (P(miss) ~= 6*(5/6)^4096 ~ 0), so we finish after ONE load + ONE barrier.
//  Phase 2 (exactness fallback, taken only if phase 1's mask != 0x3F — e.g.
//    a truly absent class, or harness-poisoned constant inputs): stream the
//    remaining 1008 KB of the batch with NO per-iteration barriers and NO
//    early-exit checks, OR-accumulating in registers. This is BW/ILP-bound
//    (~64 MiB total across 64 blocks) instead of barrier-latency-bound —
//    the previous version paid 2 __syncthreads + an LDS atomic per 16 KB,
//    making a full scan ~3x slower than a pure stream.
// Both phases are exact: presence is a monotone OR; nothing is sampled away.

#define NCLASS 6
#define NBATCH 64
#define PER_BATCH (512 * 512)       // int32 elements per batch image
#define PK_THREADS 1024             // 16 waves

__global__ __launch_bounds__(PK_THREADS) void presence_kernel(
    const int* __restrict__ target, unsigned* __restrict__ masks) {
    const int batch = blockIdx.x;
    const int4* __restrict__ p =
        (const int4*)(target + (size_t)batch * PER_BATCH);
    const int tid = (int)threadIdx.x;

    __shared__ unsigned sm;
    if (tid == 0) sm = 0u;
    __syncthreads();

    // ---- Phase 1: single 16 KB probe (1024 threads x int4 = 4096 labels).
    {
        int4 v = p[tid];
        unsigned m = (1u << v.x) | (1u << v.y) | (1u << v.z) | (1u << v.w);
#pragma unroll
        for (int off = 32; off > 0; off >>= 1)
            m |= (unsigned)__shfl_down((int)m, off, 64);
        if ((tid & 63) == 0) atomicOr(&sm, m);
    }
    __syncthreads();
    // sm is uniform here (all atomicOrs precede the barrier) -> uniform branch.

    if (sm != 0x3Fu) {
        // ---- Phase 2: barrier-free streaming scan of the remainder.
        const int NV = PER_BATCH / 4;           // 65536 int4 per batch
        unsigned acc = 0u;
#pragma unroll 4
        for (int base = PK_THREADS; base < NV; base += PK_THREADS) {
            int4 w = p[base + tid];             // coalesced 16 KB/block/iter
            acc |= (1u << w.x) | (1u << w.y) | (1u << w.z) | (1u << w.w);
        }
#pragma unroll
        for (int off = 32; off > 0; off >>= 1)
            acc |= (unsigned)__shfl_down((int)acc, off, 64);
        if ((tid & 63) == 0) atomicOr(&sm, acc);
        __syncthreads();
    }

    if (tid == 0) masks[batch] = sm;
}

// BCE epilogue over 64*6 = 384 terms, single block.
__global__ __launch_bounds__(384) void bce_kernel(
    const float* __restrict__ se_pred, const unsigned* __restrict__ masks,
    float* __restrict__ out) {
    const int i = (int)threadIdx.x;          // 0..383  == b*NCLASS + c
    const int b = i / NCLASS;
    const int c = i % NCLASS;

    const float p = se_pred[i];
    const float t = ((masks[b] >> c) & 1u) ? 1.0f : 0.0f;
    // torch BCELoss clamps log outputs at -100
    const float lp  = fmaxf(logf(p), -100.0f);
    const float l1p = fmaxf(log1pf(-p), -100.0f);
    float term = -(t * lp + (1.0f - t) * l1p);

    // Reduce within each wave (6 waves), then across waves in LDS.
#pragma unroll
    for (int off = 32; off > 0; off >>= 1)
        term += __shfl_down(term, off, 64);

    __shared__ float partial[6];
    if ((threadIdx.x & 63) == 0) partial[threadIdx.x >> 6] = term;
    __syncthreads();
    if (threadIdx.x == 0) {
        float s = 0.0f;
#pragma unroll
        for (int w = 0; w < 6; ++w) s += partial[w];
        out[0] = s * (1.0f / (NBATCH * NCLASS));
    }
}

extern "C" void kernel_launch(void* const* d_in, const int* in_sizes, int n_in,
                              void* d_out, int out_size, void* d_ws, size_t ws_size,
                              hipStream_t stream) {
    const float* se_pred = (const float*)d_in[0];   // [64,6] fp32
    const int*   target  = (const int*)d_in[1];     // [64,512,512] int32
    float*       out     = (float*)d_out;           // scalar fp32
    unsigned*    masks   = (unsigned*)d_ws;         // 64 presence bitmasks

    // masks are plain-stored (not accumulated) -> no zero-init dispatch needed.
    presence_kernel<<<NBATCH, PK_THREADS, 0, stream>>>(target, masks);
    bce_kernel<<<1, 384, 0, stream>>>(se_pred, masks, out);
}